// Round 8
// baseline (3040.681 us; speedup 1.0000x reference)
//
#include <hip/hip_runtime.h>
#include <math.h>

// Problem constants (fixed by setup_inputs)
#define NN   256   // nodes
#define HH   450   // hidden
#define LATD 56    // latent
#define VV   780   // vocab
#define LL   511   // path length (2N-1)
#define GSEQ 16    // persistent blocks (halved: straggler max + poll storm)
#define TSEQ 512   // threads per persistent block
#define AST  32    // accumulator row stride (pad 29 -> 32)
#define NIT  4     // row iterations per wave (4*8=32 >= 29 rows)
#define RING 8     // exclusion-history ring depth (also RAW-safety margin)

__device__ __forceinline__ float wred_sum(float v) {
    for (int off = 32; off; off >>= 1) v += __shfl_down(v, off, 64);
    return v;
}

// fast sigmoid/tanh via v_exp (adequate for 3e-2 tolerance)
__device__ __forceinline__ float fsig(float x) {
    return 1.f / (1.f + __expf(-x));
}
__device__ __forceinline__ float ftanh(float x) {
    const float t = fabsf(x);
    const float e = __expf(-2.f * t);
    const float r = (1.f - e) / (1.f + e);
    return x < 0.f ? -r : r;
}

// ---- raw workgroup barrier: LDS-ordering only (no vmcnt(0) drain). ----
__device__ __forceinline__ void barrier_lds() {
    asm volatile("s_waitcnt lgkmcnt(0)" ::: "memory");
    __builtin_amdgcn_s_barrier();
}

// ---- agent-scope relaxed mailbox ops ----
__device__ __forceinline__ void ast64(unsigned long long* p, unsigned long long v) {
    __hip_atomic_store(p, v, __ATOMIC_RELAXED, __HIP_MEMORY_SCOPE_AGENT);
}
__device__ __forceinline__ unsigned long long ald64(const unsigned long long* p) {
    return __hip_atomic_load(p, __ATOMIC_RELAXED, __HIP_MEMORY_SCOPE_AGENT);
}
__device__ __forceinline__ unsigned long long pk64(float v, unsigned tag) {
    return ((unsigned long long)tag << 32) | (unsigned long long)__float_as_uint(v);
}
__device__ __forceinline__ float lo32f(unsigned long long x) { return __uint_as_float((unsigned)x); }
__device__ __forceinline__ unsigned hi32(unsigned long long x) { return (unsigned)(x >> 32); }

// ---- pipelined poll: 6 outstanding rotating loads (detection ~RT/6) ----
__device__ __forceinline__ float poll6(const unsigned long long* pp, unsigned tag) {
    unsigned long long a = ald64(pp);
    if (hi32(a) == tag) return lo32f(a);
    unsigned long long b = ald64(pp);
    unsigned long long c = ald64(pp);
    unsigned long long d = ald64(pp);
    unsigned long long e = ald64(pp);
    unsigned long long f = ald64(pp);
    for (;;) {
        if (hi32(a) == tag) return lo32f(a);
        a = b; b = c; c = d; d = e; e = f; f = ald64(pp);
    }
}

// ---- find vocab id of each node's one-hot feature ----
__global__ void k_vid(const float* __restrict__ nf, int* __restrict__ vid) {
    const int u = blockIdx.x;
    for (int v = threadIdx.x; v < VV; v += blockDim.x)
        if (nf[(size_t)u * VV + v] > 0.5f) vid[u] = v;
}

// ---- per-node constants: cz, r1, sigma(r1), ch, and Ud . relu(d12) scalar ----
__global__ __launch_bounds__(512) void k_consts(
    const int* __restrict__ vid, const float* __restrict__ latent,
    const float* __restrict__ Wz, const float* __restrict__ Wzb,
    const float* __restrict__ Wr, const float* __restrict__ Wrb,
    const float* __restrict__ Wh, const float* __restrict__ Whb,
    const float* __restrict__ Wd12, const float* __restrict__ Wd12b,
    const float* __restrict__ Ud,
    float* __restrict__ cz, float* __restrict__ r1s, float* __restrict__ sig0,
    float* __restrict__ ch, float* __restrict__ dotd12)
{
    const int u = blockIdx.x, tid = threadIdx.x;
    const int v = vid[u];
    __shared__ float red[8];
    float p = 0.f;
    if (tid < HH) {
        const int i = tid, o = u * HH + i;
        cz[o] = Wz[(size_t)i * (VV + HH) + v] + Wzb[i];
        const float r1 = Wr[(size_t)i * VV + v] + Wrb[i];
        r1s[o] = r1;
        sig0[o] = 1.f / (1.f + expf(-r1));
        ch[o] = Wh[(size_t)i * (VV + HH) + v] + Whb[i];
        float d = Wd12[(size_t)i * (VV + LATD) + v] + Wd12b[i];
        for (int k = 0; k < LATD; ++k)
            d += Wd12[(size_t)i * (VV + LATD) + VV + k] * latent[k];
        p = Ud[i] * fmaxf(d, 0.f);
    }
    p = wred_sum(p);
    if ((tid & 63) == 0) red[tid >> 6] = p;
    __syncthreads();
    if (tid == 0) {
        float s = 0.f;
        for (int w = 0; w < 8; ++w) s += red[w];
        dotd12[u] = s;
    }
}

// ---- WhSig0[u] = Wh_H @ sigma(r1[u]) ----
__global__ __launch_bounds__(512) void k_whsig0(
    const float* __restrict__ Wh, const float* __restrict__ sig0, float* __restrict__ out)
{
    const int u = blockIdx.x, tid = threadIdx.x, wave = tid >> 6, lane = tid & 63;
    __shared__ float sg[HH];
    if (tid < HH) sg[tid] = sig0[u * HH + tid];
    __syncthreads();
    for (int r = wave; r < HH; r += 8) {
        float acc = 0.f;
        for (int k = lane; k < HH; k += 64)
            acc += Wh[(size_t)r * (VV + HH) + VV + k] * sg[k];
        acc = wred_sum(acc);
        if (lane == 0) out[u * HH + r] = acc;
    }
}

// ---- per-step exclusion index + precomputed neighbor-count coefficient ----
__global__ void k_excl(const int* __restrict__ node_ids, const int* __restrict__ next_ids,
                       int* __restrict__ excl, float* __restrict__ ccpre)
{
    const int t = blockIdx.x;
    __shared__ int ex, cnt;
    if (threadIdx.x == 0) { ex = -1; cnt = 0; }
    __syncthreads();
    const int a = node_ids[t], b = next_ids[t];
    for (int tp = threadIdx.x; tp <= t; tp += blockDim.x) {
        if (tp < t && node_ids[tp] == b && next_ids[tp] == a) ex = tp;
        if (tp >= 1 && node_ids[tp] == a) atomicAdd(&cnt, 1);
    }
    __syncthreads();
    if (threadIdx.x == 0) {
        excl[t] = ex;
        ccpre[t] = 256.f - (float)cnt + (ex >= 0 ? 1.f : 0.f);
    }
}

// ---- copy stops/real_labels into d_out; zero the pred_stop region ----
__global__ void k_copy(const int* __restrict__ stops, const int* __restrict__ reall,
                       float* __restrict__ out)
{
    const int i = blockIdx.x * blockDim.x + threadIdx.x;
    if (i < LL) { out[i] = (float)stops[i]; out[LL + i] = 0.f; }
    if (i < NN) out[2 * LL + i] = (float)reall[i];
}

// ---- final pred_stop reduction: sum 16 per-block partials per step ----
__global__ void k_pred(const float* __restrict__ pred_part, float* __restrict__ out) {
    const int t = blockIdx.x * blockDim.x + threadIdx.x;
    if (t < LL) {
        float s = 0.f;
        #pragma unroll 8
        for (int b = 0; b < GSEQ; ++b) s += pred_part[(size_t)t * GSEQ + b];
        out[LL + t] = s;
    }
}

// one-shot keep: asm-defined SSA values cannot be rematerialized as loads.
#define KEEP16(w) asm volatile("" : \
    "+v"((w)[0]), "+v"((w)[1]), "+v"((w)[2]),  "+v"((w)[3]),  "+v"((w)[4]),  "+v"((w)[5]),  "+v"((w)[6]),  "+v"((w)[7]), \
    "+v"((w)[8]), "+v"((w)[9]), "+v"((w)[10]), "+v"((w)[11]), "+v"((w)[12]), "+v"((w)[13]), "+v"((w)[14]), "+v"((w)[15]))

// ---- sequential scan: ROW-partitioned, broadcast-only exchange ----
// GSEQ=16 blocks (29/28 rows each). Round-5 protocol (the measured best):
// mailbox stores issue immediately from the computing lane; polls by all
// threads except own rows; 3 lgkmcnt-only barriers per step. Halving the
// participant count halves the straggler population (every step waits on
// the slowest producer twice) and the poll storm on the mailbox lines,
// while compute grows from a 2%-VALUBusy base.
__global__ __launch_bounds__(TSEQ, 1) void k_seq(
    const int* __restrict__ node_ids, const int* __restrict__ excl,
    const float* __restrict__ ccpre,
    const float* __restrict__ Ur, const float* __restrict__ Wz,
    const float* __restrict__ Wh, const float* __restrict__ Wd3,
    const float* __restrict__ Wd3b, const float* __restrict__ Ud,
    const float* __restrict__ Udb,
    const float* __restrict__ cz, const float* __restrict__ r1s,
    const float* __restrict__ ch, const float* __restrict__ WhSig0,
    const float* __restrict__ dotd12,
    float* __restrict__ NewHL, float* __restrict__ WzML, float* __restrict__ WhSvL,
    unsigned long long* __restrict__ bcNh, unsigned long long* __restrict__ bcSig,
    float* __restrict__ pred_part)
{
    const int tid = threadIdx.x, bid = blockIdx.x;
    const int wave = tid >> 6, lane = tid & 63;
    const int kcnt = 28 + (bid < 2 ? 1 : 0);
    const int kbeg = 28 * bid + (bid < 2 ? bid : 2);

    float* myNewH = NewHL  + (size_t)bid * LL * AST;
    float* myWzM  = WzML   + (size_t)bid * LL * AST;
    float* myWhSv = WhSvL  + (size_t)bid * LL * AST;

    __shared__ float sSm[NN * AST];     // per-node Sm    (own rows)   32KB
    __shared__ float sWzSm[NN * AST];   // per-node WzSm  (own rows)   32KB
    __shared__ float sWhRs[NN * AST];   // per-node WhRs  (own rows)   32KB
    __shared__ float sWd3S[NN * AST];   // per-node Wd3Sm (own rows)   32KB
    __shared__ float nh_full[512];
    __shared__ float sig_full[512];
    __shared__ float sNhR[RING][AST];   // recent-step rings for exclusion
    __shared__ float sWzR[RING][AST];
    __shared__ float sWhR[RING][AST];

    // ---- own-row weight slices (row j = wave + 8*it, cols lane+64e) ----
    float urw[NIT * 8], wzw[NIT * 8], wd3w[NIT * 8], whw[NIT * 8];
    #pragma unroll
    for (int it = 0; it < NIT; ++it) {
        const int j = wave + 8 * it;
        const bool vj = j < kcnt;
        const int r = vj ? (kbeg + j) : 0;
        #pragma unroll
        for (int e = 0; e < 8; ++e) {
            const int c = lane + 64 * e;
            const bool vc = vj && (c < HH);
            urw[it * 8 + e]  = vc ? Ur[(size_t)r * HH + c] : 0.f;
            wzw[it * 8 + e]  = vc ? Wz[(size_t)r * (VV + HH) + VV + c] : 0.f;
            wd3w[it * 8 + e] = vc ? Wd3[(size_t)r * HH + c] : 0.f;
            whw[it * 8 + e]  = vc ? Wh[(size_t)r * (VV + HH) + VV + c] : 0.f;
        }
    }
    KEEP16(urw); KEEP16(urw + 16); KEEP16(wzw); KEEP16(wzw + 16);
    KEEP16(wd3w); KEEP16(wd3w + 16); KEEP16(whw); KEEP16(whw + 16);

    // hoisted pred_stop constants
    float ud_r = 0.f, w3b_r = 0.f;
    if (tid < kcnt) { ud_r = Ud[HH + kbeg + tid]; w3b_r = Wd3b[kbeg + tid]; }
    const float udb0 = Udb[0];

    // zero LDS state
    for (int i = tid; i < NN * AST; i += TSEQ) {
        sSm[i] = 0.f; sWzSm[i] = 0.f; sWhRs[i] = 0.f; sWd3S[i] = 0.f;
    }
    nh_full[tid] = 0.f; sig_full[tid] = 0.f;

    // prefetched A-constants for iteration t=1 (ap = node_ids[0])
    int ap = node_ids[0];
    float pcz = 0.f, pch = 0.f, pws = 0.f;
    if (tid < kcnt) {
        const int o = ap * HH + kbeg + tid;
        pcz = cz[o]; pch = ch[o]; pws = WhSig0[o];
    }
    float pcc = ccpre[0];
    int  pidx = excl[0];
    float pe_nh = 0.f, pe_wz = 0.f, pe_wh = 0.f;   // prefetched ring-miss excl
    const bool own_row = tid >= kbeg && tid < kbeg + kcnt;   // skip self-poll
    __syncthreads();   // full barrier once, before the loop

    for (int t = 1; t <= LL; ++t) {
        const int idx = pidx;
        // ---- A: new_h(t-1) own rows (LDS state + prefetched consts) ----
        float nh = 0.f;
        if (tid < kcnt) {
            const int oa = ap * AST + tid;
            float zarg = sWzSm[oa] + pcz;
            float whv  = sWhRs[oa] + pch;
            float sv   = sSm[oa];
            if (idx >= 0) {
                float enh, ewz, ewh;
                if (idx >= t - RING) {       // in LDS ring
                    const int sl = idx & (RING - 1);
                    enh = sNhR[sl][tid]; ewz = sWzR[sl][tid]; ewh = sWhR[sl][tid];
                } else {                     // prefetched last iteration
                    enh = pe_nh; ewz = pe_wz; ewh = pe_wh;
                }
                zarg -= ewz; whv -= ewh; sv -= enh;
            }
            whv += pcc * pws;
            const float z = fsig(zarg);
            nh = (1.f - z) * sv + z * ftanh(whv);
            if (t < LL) {                     // broadcast own rows ASAP
                ast64(&bcNh[(size_t)((t & 1) * 512 + kbeg + tid)], pk64(nh, (unsigned)t));
                nh_full[kbeg + tid] = nh;     // local fast path (no self-poll)
            }
            myNewH[(size_t)(t - 1) * AST + tid] = nh;
            sNhR[(t - 1) & (RING - 1)][tid] = nh;
        }
        // pred_stop(t-1): own rows (kcnt<=29) live in wave 0; per-block store
        if (wave == 0) {
            float ps = 0.f;
            if (tid < kcnt)
                ps = ud_r * fmaxf(sWd3S[ap * AST + tid] + w3b_r, 0.f);
            ps = wred_sum(ps);
            if (lane == 0) {
                if (bid == 0) ps += dotd12[ap] + udb0;
                pred_part[(size_t)(t - 1) * GSEQ + bid] = ps;
            }
        }
        if (t == LL) break;   // last step: no ingestion (is_last masked)
        const int a = node_ids[t];
        const unsigned tag = (unsigned)t;
        const int p = t & 1;

        // ---- prefetches (overlap nh RT) ----
        pidx = excl[t];
        pe_nh = pe_wz = pe_wh = 0.f;
        if (pidx >= 0 && pidx < t - (RING - 1) && tid < kcnt) {
            const int oe = pidx * AST + tid;
            pe_nh = myNewH[oe]; pe_wz = myWzM[oe]; pe_wh = myWhSv[oe];
        }
        float r1v[NIT];
        #pragma unroll
        for (int it = 0; it < NIT; ++it) {
            const int j = wave + 8 * it;
            r1v[it] = r1s[(size_t)a * HH + ((j < kcnt) ? (kbeg + j) : 0)];
        }
        float ncz = 0.f, nch = 0.f, nws = 0.f;
        if (tid < kcnt) {
            const int o = a * HH + kbeg + tid;
            ncz = cz[o]; nch = ch[o]; nws = WhSig0[o];
        }
        const float ncc = ccpre[t];
        if (tid < kcnt) sSm[a * AST + tid] += nh;   // local Sm fold

        // ---- poll nh broadcast (pipelined; skip own rows) ----
        if (tid < HH && !own_row)
            nh_full[tid] = poll6(&bcNh[(size_t)(p * 512 + tid)], tag);
        barrier_lds();   // S1: nh_full ready

        // ---- critical: Ur dot -> sigma -> broadcast (store immediately) ----
        #pragma unroll
        for (int it = 0; it < NIT; ++it) {
            const int j = wave + 8 * it;
            float acc = 0.f;
            #pragma unroll
            for (int e = 0; e < 8; ++e) acc += urw[it * 8 + e] * nh_full[lane + 64 * e];
            acc = wred_sum(acc);
            if (lane == 0 && j < kcnt) {
                const float sg = fsig(acc + r1v[it]);
                ast64(&bcSig[(size_t)(p * 512 + kbeg + j)], pk64(sg, tag));
                sig_full[kbeg + j] = sg;      // local fast path
            }
        }

        // ---- off-critical: Wz & Wd3 dots + folds (hide sig RT) ----
        #pragma unroll
        for (int it = 0; it < NIT; ++it) {
            const int j = wave + 8 * it;
            float az = 0.f, ad = 0.f;
            #pragma unroll
            for (int e = 0; e < 8; ++e) {
                const float x = nh_full[lane + 64 * e];
                az += wzw[it * 8 + e] * x;
                ad += wd3w[it * 8 + e] * x;
            }
            az = wred_sum(az); ad = wred_sum(ad);
            if (lane == 0 && j < kcnt) {
                myWzM[(size_t)(t - 1) * AST + j] = az;
                sWzR[(t - 1) & (RING - 1)][j] = az;
                sWzSm[a * AST + j] += az;
                sWd3S[a * AST + j] += ad;
            }
        }
        pcz = ncz; pch = nch; pws = nws; pcc = ncc;

        // ---- poll sigma broadcast (pipelined; skip own rows) ----
        if (tid < HH && !own_row)
            sig_full[tid] = poll6(&bcSig[(size_t)(p * 512 + tid)], tag);
        barrier_lds();   // S2: sig_full ready

        // ---- Wh dot + fold ----
        #pragma unroll
        for (int it = 0; it < NIT; ++it) {
            const int j = wave + 8 * it;
            float aw = 0.f;
            #pragma unroll
            for (int e = 0; e < 8; ++e) aw += whw[it * 8 + e] * sig_full[lane + 64 * e];
            aw = wred_sum(aw);
            if (lane == 0 && j < kcnt) {
                myWhSv[(size_t)(t - 1) * AST + j] = aw;
                sWhR[(t - 1) & (RING - 1)][j] = aw;
                sWhRs[a * AST + j] += aw;
            }
        }
        ap = a;
        barrier_lds();   // S3: folds visible before next A
    }
}

// ---- labels: root (q=0, outer relu, no softmax) + 255 label steps (softmax) ----
__global__ __launch_bounds__(512) void k_label(
    const float* __restrict__ latent, const int* __restrict__ lsteps,
    const float* __restrict__ NewHL,
    const float* __restrict__ Wl, const float* __restrict__ Wlb,
    const float* __restrict__ Ul, const float* __restrict__ Ulb,
    float* __restrict__ out)
{
    const int q = blockIdx.x, tid = threadIdx.x, wave = tid >> 6, lane = tid & 63;
    __shared__ float inp[LATD + HH];
    __shared__ float t2[HH];
    __shared__ float lg[VV];
    __shared__ float red[8];
    if (tid < LATD) inp[tid] = latent[tid];
    if (q == 0) {
        if (tid < HH) inp[LATD + tid] = 0.f;
    } else {
        const int t = lsteps[q - 1];
        if (tid < HH) {
            const int b = (tid < 58) ? (tid / 29) : (2 + (tid - 58) / 28);
            const int j = (tid < 58) ? (tid % 29) : ((tid - 58) % 28);
            inp[LATD + tid] = NewHL[((size_t)b * LL + t) * AST + j];
        }
    }
    __syncthreads();
    for (int r = wave; r < HH; r += 8) {
        float acc = 0.f;
        for (int k = lane; k < LATD + HH; k += 64)
            acc += Wl[(size_t)r * (LATD + HH) + k] * inp[k];
        acc = wred_sum(acc);
        if (lane == 0) {
            const float v = acc + Wlb[r];
            t2[r] = (q == 0) ? v : fmaxf(v, 0.f);   // root: no inner relu
        }
    }
    __syncthreads();
    for (int r = wave; r < VV; r += 8) {
        float acc = 0.f;
        for (int k = lane; k < HH; k += 64) acc += Ul[(size_t)r * HH + k] * t2[k];
        acc = wred_sum(acc);
        if (lane == 0) lg[r] = acc + Ulb[r];
    }
    __syncthreads();
    float* outrow = out + 2 * LL + NN + (size_t)q * VV;
    if (q == 0) {   // root: relu, no softmax
        for (int i = tid; i < VV; i += 512) outrow[i] = fmaxf(lg[i], 0.f);
        return;
    }
    float mx = -1e30f;
    for (int i = tid; i < VV; i += 512) mx = fmaxf(mx, lg[i]);
    for (int off = 32; off; off >>= 1) mx = fmaxf(mx, __shfl_down(mx, off, 64));
    if (lane == 0) red[wave] = mx;
    __syncthreads();
    if (tid == 0) {
        float m = red[0];
        for (int w = 1; w < 8; ++w) m = fmaxf(m, red[w]);
        red[0] = m;
    }
    __syncthreads();
    const float M = red[0];
    float sum = 0.f;
    for (int i = tid; i < VV; i += 512) { const float e = expf(lg[i] - M); lg[i] = e; sum += e; }
    __syncthreads();
    sum = wred_sum(sum);
    if (lane == 0) red[wave] = sum;
    __syncthreads();
    if (tid == 0) {
        float s = 0.f;
        for (int w = 0; w < 8; ++w) s += red[w];
        red[0] = s;
    }
    __syncthreads();
    const float S = red[0];
    for (int i = tid; i < VV; i += 512) outrow[i] = lg[i] / S;
}

extern "C" void kernel_launch(void* const* d_in, const int* in_sizes, int n_in,
                              void* d_out, int out_size, void* d_ws, size_t ws_size,
                              hipStream_t stream)
{
    const float* latent = (const float*)d_in[0];
    const float* nodef  = (const float*)d_in[1];
    const int* node_ids = (const int*)d_in[2];
    const int* next_ids = (const int*)d_in[3];
    const int* stops    = (const int*)d_in[4];
    const int* lsteps   = (const int*)d_in[5];
    const int* reall    = (const int*)d_in[6];
    const float* Wz   = (const float*)d_in[7];
    const float* Wzb  = (const float*)d_in[8];
    const float* Urw  = (const float*)d_in[9];
    const float* Wr   = (const float*)d_in[10];
    const float* Wrb  = (const float*)d_in[11];
    const float* Wh   = (const float*)d_in[12];
    const float* Whb  = (const float*)d_in[13];
    const float* Wd12 = (const float*)d_in[14];
    const float* Wd12b= (const float*)d_in[15];
    const float* Wd3  = (const float*)d_in[16];
    const float* Wd3b = (const float*)d_in[17];
    const float* Ud   = (const float*)d_in[18];
    const float* Udb  = (const float*)d_in[19];
    const float* Wl   = (const float*)d_in[20];
    const float* Wlb  = (const float*)d_in[21];
    const float* Ul   = (const float*)d_in[22];
    const float* Ulb  = (const float*)d_in[23];
    (void)in_sizes; (void)n_in; (void)out_size; (void)ws_size;
    float* out = (float*)d_out;
    float* W = (float*)d_ws;

    size_t o = 0;
    unsigned long long* bcNh  = (unsigned long long*)(W + o); o += 2 * 512 * 2;
    unsigned long long* bcSig = (unsigned long long*)(W + o); o += 2 * 512 * 2;
    const size_t zero_floats = o;           // everything above must start at 0
    int*   vid    = (int*)(W + o); o += NN;
    int*   excl   = (int*)(W + o); o += LL + 1;
    float* ccpre  = W + o; o += LL + 1;
    float* cz     = W + o; o += NN * HH;
    float* r1s    = W + o; o += NN * HH;
    float* sig0   = W + o; o += NN * HH;
    float* ch     = W + o; o += NN * HH;
    float* WhSig0 = W + o; o += NN * HH;
    float* dotd12 = W + o; o += NN;
    float* NewHL  = W + o; o += (size_t)GSEQ * LL * AST;
    float* WzML   = W + o; o += (size_t)GSEQ * LL * AST;
    float* WhSvL  = W + o; o += (size_t)GSEQ * LL * AST;
    float* predp  = W + o; o += (size_t)LL * GSEQ;

    hipMemsetAsync(W, 0, zero_floats * sizeof(float), stream);
    k_vid   <<<NN, 256, 0, stream>>>(nodef, vid);
    k_consts<<<NN, 512, 0, stream>>>(vid, latent, Wz, Wzb, Wr, Wrb, Wh, Whb,
                                     Wd12, Wd12b, Ud, cz, r1s, sig0, ch, dotd12);
    k_whsig0<<<NN, 512, 0, stream>>>(Wh, sig0, WhSig0);
    k_excl  <<<LL, 256, 0, stream>>>(node_ids, next_ids, excl, ccpre);
    k_copy  <<<2, 256, 0, stream>>>(stops, reall, out);
    k_seq   <<<GSEQ, TSEQ, 0, stream>>>(node_ids, excl, ccpre, Urw, Wz, Wh, Wd3, Wd3b,
                                        Ud, Udb, cz, r1s, ch, WhSig0, dotd12,
                                        NewHL, WzML, WhSvL,
                                        bcNh, bcSig,
                                        predp);
    k_pred  <<<1, 512, 0, stream>>>(predp, out);
    k_label <<<NN, 512, 0, stream>>>(latent, lsteps, NewHL, Wl, Wlb, Ul, Ulb, out);
}

// Round 9
// 2160.976 us; speedup vs baseline: 1.4071x; 1.4071x over previous
//
#include <hip/hip_runtime.h>
#include <math.h>

// Problem constants (fixed by setup_inputs)
#define NN   256   // nodes
#define HH   450   // hidden
#define LATD 56    // latent
#define VV   780   // vocab
#define LL   511   // path length (2N-1)
#define GSEQ 32    // persistent blocks (round-5 optimum)
#define TSEQ 512   // threads per persistent block
#define KMAX 15    // max rows per block (450 = 15+15+14*30)
#define AST  16    // accumulator row stride (pad 15 -> 16)
#define RING 8     // exclusion-history ring depth (also RAW-safety margin)

__device__ __forceinline__ float wred_sum(float v) {
    for (int off = 32; off; off >>= 1) v += __shfl_down(v, off, 64);
    return v;
}

// fast sigmoid/tanh via v_exp (validated: absmax unchanged at 3e-2 tol)
__device__ __forceinline__ float fsig(float x) {
    return 1.f / (1.f + __expf(-x));
}
__device__ __forceinline__ float ftanh(float x) {
    const float t = fabsf(x);
    const float e = __expf(-2.f * t);
    const float r = (1.f - e) / (1.f + e);
    return x < 0.f ? -r : r;
}

// ---- raw workgroup barrier: LDS-ordering only (no vmcnt(0) drain). ----
__device__ __forceinline__ void barrier_lds() {
    asm volatile("s_waitcnt lgkmcnt(0)" ::: "memory");
    __builtin_amdgcn_s_barrier();
}

// ---- agent-scope relaxed mailbox ops ----
__device__ __forceinline__ void ast64(unsigned long long* p, unsigned long long v) {
    __hip_atomic_store(p, v, __ATOMIC_RELAXED, __HIP_MEMORY_SCOPE_AGENT);
}
__device__ __forceinline__ unsigned long long ald64(const unsigned long long* p) {
    return __hip_atomic_load(p, __ATOMIC_RELAXED, __HIP_MEMORY_SCOPE_AGENT);
}
__device__ __forceinline__ unsigned long long pk64(float v, unsigned tag) {
    return ((unsigned long long)tag << 32) | (unsigned long long)__float_as_uint(v);
}
__device__ __forceinline__ float lo32f(unsigned long long x) { return __uint_as_float((unsigned)x); }
__device__ __forceinline__ unsigned hi32(unsigned long long x) { return (unsigned)(x >> 32); }

// ---- pipelined poll: 6 outstanding rotating loads (detection ~RT/6).
// In-order vmcnt rule: a poll check queued behind the SAME thread's
// agent-store (~1000cy ack) waits for the store first -- so the poll
// mapping below guarantees producers never poll (zero-barrier fix for
// the r7 diagnosis; r7's hand-off barrier implementation regressed).
__device__ __forceinline__ float poll6(const unsigned long long* pp, unsigned tag) {
    unsigned long long a = ald64(pp);
    if (hi32(a) == tag) return lo32f(a);
    unsigned long long b = ald64(pp);
    unsigned long long c = ald64(pp);
    unsigned long long d = ald64(pp);
    unsigned long long e = ald64(pp);
    unsigned long long f = ald64(pp);
    for (;;) {
        if (hi32(a) == tag) return lo32f(a);
        a = b; b = c; c = d; d = e; e = f; f = ald64(pp);
    }
}

// ---- find vocab id of each node's one-hot feature ----
__global__ void k_vid(const float* __restrict__ nf, int* __restrict__ vid) {
    const int u = blockIdx.x;
    for (int v = threadIdx.x; v < VV; v += blockDim.x)
        if (nf[(size_t)u * VV + v] > 0.5f) vid[u] = v;
}

// ---- per-node constants: cz, r1, sigma(r1), ch, and Ud . relu(d12) scalar ----
__global__ __launch_bounds__(512) void k_consts(
    const int* __restrict__ vid, const float* __restrict__ latent,
    const float* __restrict__ Wz, const float* __restrict__ Wzb,
    const float* __restrict__ Wr, const float* __restrict__ Wrb,
    const float* __restrict__ Wh, const float* __restrict__ Whb,
    const float* __restrict__ Wd12, const float* __restrict__ Wd12b,
    const float* __restrict__ Ud,
    float* __restrict__ cz, float* __restrict__ r1s, float* __restrict__ sig0,
    float* __restrict__ ch, float* __restrict__ dotd12)
{
    const int u = blockIdx.x, tid = threadIdx.x;
    const int v = vid[u];
    __shared__ float red[8];
    float p = 0.f;
    if (tid < HH) {
        const int i = tid, o = u * HH + i;
        cz[o] = Wz[(size_t)i * (VV + HH) + v] + Wzb[i];
        const float r1 = Wr[(size_t)i * VV + v] + Wrb[i];
        r1s[o] = r1;
        sig0[o] = 1.f / (1.f + expf(-r1));
        ch[o] = Wh[(size_t)i * (VV + HH) + v] + Whb[i];
        float d = Wd12[(size_t)i * (VV + LATD) + v] + Wd12b[i];
        for (int k = 0; k < LATD; ++k)
            d += Wd12[(size_t)i * (VV + LATD) + VV + k] * latent[k];
        p = Ud[i] * fmaxf(d, 0.f);
    }
    p = wred_sum(p);
    if ((tid & 63) == 0) red[tid >> 6] = p;
    __syncthreads();
    if (tid == 0) {
        float s = 0.f;
        for (int w = 0; w < 8; ++w) s += red[w];
        dotd12[u] = s;
    }
}

// ---- WhSig0[u] = Wh_H @ sigma(r1[u]) ----
__global__ __launch_bounds__(512) void k_whsig0(
    const float* __restrict__ Wh, const float* __restrict__ sig0, float* __restrict__ out)
{
    const int u = blockIdx.x, tid = threadIdx.x, wave = tid >> 6, lane = tid & 63;
    __shared__ float sg[HH];
    if (tid < HH) sg[tid] = sig0[u * HH + tid];
    __syncthreads();
    for (int r = wave; r < HH; r += 8) {
        float acc = 0.f;
        for (int k = lane; k < HH; k += 64)
            acc += Wh[(size_t)r * (VV + HH) + VV + k] * sg[k];
        acc = wred_sum(acc);
        if (lane == 0) out[u * HH + r] = acc;
    }
}

// ---- per-step exclusion index + precomputed neighbor-count coefficient ----
__global__ void k_excl(const int* __restrict__ node_ids, const int* __restrict__ next_ids,
                       int* __restrict__ excl, float* __restrict__ ccpre)
{
    const int t = blockIdx.x;
    __shared__ int ex, cnt;
    if (threadIdx.x == 0) { ex = -1; cnt = 0; }
    __syncthreads();
    const int a = node_ids[t], b = next_ids[t];
    for (int tp = threadIdx.x; tp <= t; tp += blockDim.x) {
        if (tp < t && node_ids[tp] == b && next_ids[tp] == a) ex = tp;
        if (tp >= 1 && node_ids[tp] == a) atomicAdd(&cnt, 1);
    }
    __syncthreads();
    if (threadIdx.x == 0) {
        excl[t] = ex;
        ccpre[t] = 256.f - (float)cnt + (ex >= 0 ? 1.f : 0.f);
    }
}

// ---- copy stops/real_labels into d_out; zero the pred_stop region ----
__global__ void k_copy(const int* __restrict__ stops, const int* __restrict__ reall,
                       float* __restrict__ out)
{
    const int i = blockIdx.x * blockDim.x + threadIdx.x;
    if (i < LL) { out[i] = (float)stops[i]; out[LL + i] = 0.f; }
    if (i < NN) out[2 * LL + i] = (float)reall[i];
}

// ---- final pred_stop reduction: sum 32 per-block partials per step ----
__global__ void k_pred(const float* __restrict__ pred_part, float* __restrict__ out) {
    const int t = blockIdx.x * blockDim.x + threadIdx.x;
    if (t < LL) {
        float s = 0.f;
        #pragma unroll 8
        for (int b = 0; b < GSEQ; ++b) s += pred_part[(size_t)t * GSEQ + b];
        out[LL + t] = s;
    }
}

// one-shot keep: asm-defined SSA values cannot be rematerialized as loads.
#define KEEP16(w) asm volatile("" : \
    "+v"(w[0]), "+v"(w[1]), "+v"(w[2]),  "+v"(w[3]),  "+v"(w[4]),  "+v"(w[5]),  "+v"(w[6]),  "+v"(w[7]), \
    "+v"(w[8]), "+v"(w[9]), "+v"(w[10]), "+v"(w[11]), "+v"(w[12]), "+v"(w[13]), "+v"(w[14]), "+v"(w[15]))

// ---- sequential scan: round-5 structure (measured best, 1976us) + poll
// remap so producers never poll + fast transcendentals.
// nh producers  = tid<kcnt           -> nh  poll by tid in [kcnt,450):
//                                       word (kbeg+tid) mod 450
// sig producers = lane0 of each wave -> sig poll by lanes 1..63:
//                                       rank=wave*63+lane-1,
//                                       word (kbeg+kcnt+rank) mod 450
// Both mappings cover exactly the non-own words once, race-free, with
// zero added barriers. Stores still issue immediately from the
// computing lane (the r7 hand-off variant regressed).
__global__ __launch_bounds__(TSEQ, 1) void k_seq(
    const int* __restrict__ node_ids, const int* __restrict__ excl,
    const float* __restrict__ ccpre,
    const float* __restrict__ Ur, const float* __restrict__ Wz,
    const float* __restrict__ Wh, const float* __restrict__ Wd3,
    const float* __restrict__ Wd3b, const float* __restrict__ Ud,
    const float* __restrict__ Udb,
    const float* __restrict__ cz, const float* __restrict__ r1s,
    const float* __restrict__ ch, const float* __restrict__ WhSig0,
    const float* __restrict__ dotd12,
    float* __restrict__ NewHL, float* __restrict__ WzML, float* __restrict__ WhSvL,
    unsigned long long* __restrict__ bcNh, unsigned long long* __restrict__ bcSig,
    float* __restrict__ pred_part)
{
    const int tid = threadIdx.x, bid = blockIdx.x;
    const int wave = tid >> 6, lane = tid & 63;
    const int kcnt = 14 + (bid < 2 ? 1 : 0);
    const int kbeg = 14 * bid + (bid < 2 ? bid : 2);

    // poll-word mappings (producers excluded by construction)
    int wnh = kbeg + tid; if (wnh >= HH) wnh -= HH;
    const bool nh_poll = (tid >= kcnt) && (tid < HH);
    const int rank = wave * 63 + lane - 1;
    int wsg = kbeg + kcnt + rank; if (wsg >= HH) wsg -= HH;
    const bool sg_poll = (lane != 0) && (rank < HH - kcnt);

    float* myNewH = NewHL  + (size_t)bid * LL * AST;
    float* myWzM  = WzML   + (size_t)bid * LL * AST;
    float* myWhSv = WhSvL  + (size_t)bid * LL * AST;

    __shared__ float sSm[NN * AST];     // per-node Sm    (own rows)
    __shared__ float sWzSm[NN * AST];   // per-node WzSm  (own rows)
    __shared__ float sWhRs[NN * AST];   // per-node WhRs  (own rows)
    __shared__ float sWd3S[NN * AST];   // per-node Wd3Sm (own rows)
    __shared__ float nh_full[512];
    __shared__ float sig_full[512];
    __shared__ float sNhR[RING][AST];   // recent-step rings for exclusion
    __shared__ float sWzR[RING][AST];
    __shared__ float sWhR[RING][AST];

    // ---- own-row weight slices (row j = wave + 8*it, cols lane+64e) ----
    float urw[16], wzw[16], wd3w[16], whw[16];
    #pragma unroll
    for (int it = 0; it < 2; ++it) {
        const int j = wave + 8 * it;
        const bool vj = j < kcnt;
        const int r = vj ? (kbeg + j) : 0;
        #pragma unroll
        for (int e = 0; e < 8; ++e) {
            const int c = lane + 64 * e;
            const bool vc = vj && (c < HH);
            urw[it * 8 + e]  = vc ? Ur[(size_t)r * HH + c] : 0.f;
            wzw[it * 8 + e]  = vc ? Wz[(size_t)r * (VV + HH) + VV + c] : 0.f;
            wd3w[it * 8 + e] = vc ? Wd3[(size_t)r * HH + c] : 0.f;
            whw[it * 8 + e]  = vc ? Wh[(size_t)r * (VV + HH) + VV + c] : 0.f;
        }
    }
    KEEP16(urw); KEEP16(wzw); KEEP16(wd3w); KEEP16(whw);   // pin once

    // hoisted pred_stop constants
    float ud_r = 0.f, w3b_r = 0.f;
    if (tid < kcnt) { ud_r = Ud[HH + kbeg + tid]; w3b_r = Wd3b[kbeg + tid]; }
    const float udb0 = Udb[0];

    // zero LDS state
    for (int i = tid; i < NN * AST; i += TSEQ) {
        sSm[i] = 0.f; sWzSm[i] = 0.f; sWhRs[i] = 0.f; sWd3S[i] = 0.f;
    }
    nh_full[tid] = 0.f; sig_full[tid] = 0.f;

    // prefetched A-constants for iteration t=1 (ap = node_ids[0])
    int ap = node_ids[0];
    float pcz = 0.f, pch = 0.f, pws = 0.f;
    if (tid < kcnt) {
        const int o = ap * HH + kbeg + tid;
        pcz = cz[o]; pch = ch[o]; pws = WhSig0[o];
    }
    float pcc = ccpre[0];
    int  pidx = excl[0];
    float pe_nh = 0.f, pe_wz = 0.f, pe_wh = 0.f;   // prefetched ring-miss excl
    __syncthreads();   // full barrier once, before the loop

    for (int t = 1; t <= LL; ++t) {
        const int idx = pidx;
        // ---- A: new_h(t-1) own rows (LDS state + prefetched consts) ----
        float nh = 0.f;
        if (tid < kcnt) {
            const int oa = ap * AST + tid;
            float zarg = sWzSm[oa] + pcz;
            float whv  = sWhRs[oa] + pch;
            float sv   = sSm[oa];
            if (idx >= 0) {
                float enh, ewz, ewh;
                if (idx >= t - RING) {       // in LDS ring
                    const int sl = idx & (RING - 1);
                    enh = sNhR[sl][tid]; ewz = sWzR[sl][tid]; ewh = sWhR[sl][tid];
                } else {                     // prefetched last iteration
                    enh = pe_nh; ewz = pe_wz; ewh = pe_wh;
                }
                zarg -= ewz; whv -= ewh; sv -= enh;
            }
            whv += pcc * pws;
            const float z = fsig(zarg);
            nh = (1.f - z) * sv + z * ftanh(whv);
            if (t < LL) {                     // broadcast own rows ASAP
                ast64(&bcNh[(size_t)((t & 1) * 512 + kbeg + tid)], pk64(nh, (unsigned)t));
                nh_full[kbeg + tid] = nh;     // local fast path (no self-poll)
            }
            myNewH[(size_t)(t - 1) * AST + tid] = nh;
            sNhR[(t - 1) & (RING - 1)][tid] = nh;
        }
        // pred_stop(t-1): own rows live in wave 0; plain per-block store
        if (wave == 0) {
            float ps = 0.f;
            if (tid < kcnt)
                ps = ud_r * fmaxf(sWd3S[ap * AST + tid] + w3b_r, 0.f);
            ps = wred_sum(ps);
            if (lane == 0) {
                if (bid == 0) ps += dotd12[ap] + udb0;
                pred_part[(size_t)(t - 1) * GSEQ + bid] = ps;
            }
        }
        if (t == LL) break;   // last step: no ingestion (is_last masked)
        const int a = node_ids[t];
        const unsigned tag = (unsigned)t;
        const int p = t & 1;

        // ---- prefetches (overlap nh RT) ----
        pidx = excl[t];
        pe_nh = pe_wz = pe_wh = 0.f;
        if (pidx >= 0 && pidx < t - (RING - 1) && tid < kcnt) {
            const int oe = pidx * AST + tid;
            pe_nh = myNewH[oe]; pe_wz = myWzM[oe]; pe_wh = myWhSv[oe];
        }
        float r1v[2];
        #pragma unroll
        for (int it = 0; it < 2; ++it) {
            const int j = wave + 8 * it;
            r1v[it] = r1s[(size_t)a * HH + ((j < kcnt) ? (kbeg + j) : 0)];
        }
        float ncz = 0.f, nch = 0.f, nws = 0.f;
        if (tid < kcnt) {
            const int o = a * HH + kbeg + tid;
            ncz = cz[o]; nch = ch[o]; nws = WhSig0[o];
        }
        const float ncc = ccpre[t];
        if (tid < kcnt) sSm[a * AST + tid] += nh;   // local Sm fold

        // ---- poll nh broadcast (producers excluded by mapping) ----
        if (nh_poll)
            nh_full[wnh] = poll6(&bcNh[(size_t)(p * 512 + wnh)], tag);
        barrier_lds();   // S1: nh_full ready

        // ---- critical: Ur dot -> sigma -> broadcast (store immediately) ----
        #pragma unroll
        for (int it = 0; it < 2; ++it) {
            const int j = wave + 8 * it;
            float acc = 0.f;
            #pragma unroll
            for (int e = 0; e < 8; ++e) acc += urw[it * 8 + e] * nh_full[lane + 64 * e];
            acc = wred_sum(acc);
            if (lane == 0 && j < kcnt) {
                const float sg = fsig(acc + r1v[it]);
                ast64(&bcSig[(size_t)(p * 512 + kbeg + j)], pk64(sg, tag));
                sig_full[kbeg + j] = sg;      // local fast path
            }
        }

        // ---- off-critical: Wz & Wd3 dots + folds (hide sig RT) ----
        #pragma unroll
        for (int it = 0; it < 2; ++it) {
            const int j = wave + 8 * it;
            float az = 0.f, ad = 0.f;
            #pragma unroll
            for (int e = 0; e < 8; ++e) {
                const float x = nh_full[lane + 64 * e];
                az += wzw[it * 8 + e] * x;
                ad += wd3w[it * 8 + e] * x;
            }
            az = wred_sum(az); ad = wred_sum(ad);
            if (lane == 0 && j < kcnt) {
                myWzM[(size_t)(t - 1) * AST + j] = az;
                sWzR[(t - 1) & (RING - 1)][j] = az;
                sWzSm[a * AST + j] += az;
                sWd3S[a * AST + j] += ad;
            }
        }
        pcz = ncz; pch = nch; pws = nws; pcc = ncc;

        // ---- poll sigma broadcast (sig producers = lane0, excluded) ----
        if (sg_poll)
            sig_full[wsg] = poll6(&bcSig[(size_t)(p * 512 + wsg)], tag);
        barrier_lds();   // S2: sig_full ready

        // ---- Wh dot + fold ----
        #pragma unroll
        for (int it = 0; it < 2; ++it) {
            const int j = wave + 8 * it;
            float aw = 0.f;
            #pragma unroll
            for (int e = 0; e < 8; ++e) aw += whw[it * 8 + e] * sig_full[lane + 64 * e];
            aw = wred_sum(aw);
            if (lane == 0 && j < kcnt) {
                myWhSv[(size_t)(t - 1) * AST + j] = aw;
                sWhR[(t - 1) & (RING - 1)][j] = aw;
                sWhRs[a * AST + j] += aw;
            }
        }
        ap = a;
        barrier_lds();   // S3: folds visible before next A
    }
}

// ---- labels: root (q=0, outer relu, no softmax) + 255 label steps (softmax) ----
__global__ __launch_bounds__(512) void k_label(
    const float* __restrict__ latent, const int* __restrict__ lsteps,
    const float* __restrict__ NewHL,
    const float* __restrict__ Wl, const float* __restrict__ Wlb,
    const float* __restrict__ Ul, const float* __restrict__ Ulb,
    float* __restrict__ out)
{
    const int q = blockIdx.x, tid = threadIdx.x, wave = tid >> 6, lane = tid & 63;
    __shared__ float inp[LATD + HH];
    __shared__ float t2[HH];
    __shared__ float lg[VV];
    __shared__ float red[8];
    if (tid < LATD) inp[tid] = latent[tid];
    if (q == 0) {
        if (tid < HH) inp[LATD + tid] = 0.f;
    } else {
        const int t = lsteps[q - 1];
        if (tid < HH) {
            const int b = (tid < 30) ? (tid / 15) : (2 + (tid - 30) / 14);
            const int j = (tid < 30) ? (tid % 15) : ((tid - 30) % 14);
            inp[LATD + tid] = NewHL[((size_t)b * LL + t) * AST + j];
        }
    }
    __syncthreads();
    for (int r = wave; r < HH; r += 8) {
        float acc = 0.f;
        for (int k = lane; k < LATD + HH; k += 64)
            acc += Wl[(size_t)r * (LATD + HH) + k] * inp[k];
        acc = wred_sum(acc);
        if (lane == 0) {
            const float v = acc + Wlb[r];
            t2[r] = (q == 0) ? v : fmaxf(v, 0.f);   // root: no inner relu
        }
    }
    __syncthreads();
    for (int r = wave; r < VV; r += 8) {
        float acc = 0.f;
        for (int k = lane; k < HH; k += 64) acc += Ul[(size_t)r * HH + k] * t2[k];
        acc = wred_sum(acc);
        if (lane == 0) lg[r] = acc + Ulb[r];
    }
    __syncthreads();
    float* outrow = out + 2 * LL + NN + (size_t)q * VV;
    if (q == 0) {   // root: relu, no softmax
        for (int i = tid; i < VV; i += 512) outrow[i] = fmaxf(lg[i], 0.f);
        return;
    }
    float mx = -1e30f;
    for (int i = tid; i < VV; i += 512) mx = fmaxf(mx, lg[i]);
    for (int off = 32; off; off >>= 1) mx = fmaxf(mx, __shfl_down(mx, off, 64));
    if (lane == 0) red[wave] = mx;
    __syncthreads();
    if (tid == 0) {
        float m = red[0];
        for (int w = 1; w < 8; ++w) m = fmaxf(m, red[w]);
        red[0] = m;
    }
    __syncthreads();
    const float M = red[0];
    float sum = 0.f;
    for (int i = tid; i < VV; i += 512) { const float e = expf(lg[i] - M); lg[i] = e; sum += e; }
    __syncthreads();
    sum = wred_sum(sum);
    if (lane == 0) red[wave] = sum;
    __syncthreads();
    if (tid == 0) {
        float s = 0.f;
        for (int w = 0; w < 8; ++w) s += red[w];
        red[0] = s;
    }
    __syncthreads();
    const float S = red[0];
    for (int i = tid; i < VV; i += 512) outrow[i] = lg[i] / S;
}

extern "C" void kernel_launch(void* const* d_in, const int* in_sizes, int n_in,
                              void* d_out, int out_size, void* d_ws, size_t ws_size,
                              hipStream_t stream)
{
    const float* latent = (const float*)d_in[0];
    const float* nodef  = (const float*)d_in[1];
    const int* node_ids = (const int*)d_in[2];
    const int* next_ids = (const int*)d_in[3];
    const int* stops    = (const int*)d_in[4];
    const int* lsteps   = (const int*)d_in[5];
    const int* reall    = (const int*)d_in[6];
    const float* Wz   = (const float*)d_in[7];
    const float* Wzb  = (const float*)d_in[8];
    const float* Urw  = (const float*)d_in[9];
    const float* Wr   = (const float*)d_in[10];
    const float* Wrb  = (const float*)d_in[11];
    const float* Wh   = (const float*)d_in[12];
    const float* Whb  = (const float*)d_in[13];
    const float* Wd12 = (const float*)d_in[14];
    const float* Wd12b= (const float*)d_in[15];
    const float* Wd3  = (const float*)d_in[16];
    const float* Wd3b = (const float*)d_in[17];
    const float* Ud   = (const float*)d_in[18];
    const float* Udb  = (const float*)d_in[19];
    const float* Wl   = (const float*)d_in[20];
    const float* Wlb  = (const float*)d_in[21];
    const float* Ul   = (const float*)d_in[22];
    const float* Ulb  = (const float*)d_in[23];
    (void)in_sizes; (void)n_in; (void)out_size; (void)ws_size;
    float* out = (float*)d_out;
    float* W = (float*)d_ws;

    size_t o = 0;
    unsigned long long* bcNh  = (unsigned long long*)(W + o); o += 2 * 512 * 2;
    unsigned long long* bcSig = (unsigned long long*)(W + o); o += 2 * 512 * 2;
    const size_t zero_floats = o;           // everything above must start at 0
    int*   vid    = (int*)(W + o); o += NN;
    int*   excl   = (int*)(W + o); o += LL + 1;
    float* ccpre  = W + o; o += LL + 1;
    float* cz     = W + o; o += NN * HH;
    float* r1s    = W + o; o += NN * HH;
    float* sig0   = W + o; o += NN * HH;
    float* ch     = W + o; o += NN * HH;
    float* WhSig0 = W + o; o += NN * HH;
    float* dotd12 = W + o; o += NN;
    float* NewHL  = W + o; o += (size_t)GSEQ * LL * AST;
    float* WzML   = W + o; o += (size_t)GSEQ * LL * AST;
    float* WhSvL  = W + o; o += (size_t)GSEQ * LL * AST;
    float* predp  = W + o; o += (size_t)LL * GSEQ;

    hipMemsetAsync(W, 0, zero_floats * sizeof(float), stream);
    k_vid   <<<NN, 256, 0, stream>>>(nodef, vid);
    k_consts<<<NN, 512, 0, stream>>>(vid, latent, Wz, Wzb, Wr, Wrb, Wh, Whb,
                                     Wd12, Wd12b, Ud, cz, r1s, sig0, ch, dotd12);
    k_whsig0<<<NN, 512, 0, stream>>>(Wh, sig0, WhSig0);
    k_excl  <<<LL, 256, 0, stream>>>(node_ids, next_ids, excl, ccpre);
    k_copy  <<<2, 256, 0, stream>>>(stops, reall, out);
    k_seq   <<<GSEQ, TSEQ, 0, stream>>>(node_ids, excl, ccpre, Urw, Wz, Wh, Wd3, Wd3b,
                                        Ud, Udb, cz, r1s, ch, WhSig0, dotd12,
                                        NewHL, WzML, WhSvL,
                                        bcNh, bcSig,
                                        predp);
    k_pred  <<<1, 512, 0, stream>>>(predp, out);
    k_label <<<NN, 512, 0, stream>>>(latent, lsteps, NewHL, Wl, Wlb, Ul, Ulb, out);
}